// Round 11
// baseline (104.318 us; speedup 1.0000x reference)
//
#include <hip/hip_runtime.h>
#include <hip/hip_bf16.h>

typedef unsigned short u16;
typedef __attribute__((ext_vector_type(8))) __bf16 bf16x8;
typedef __attribute__((ext_vector_type(4))) float f32x4;

#define B_SZ 4096
#define D_SZ 1024
#define MARGIN 0.2f

__device__ __forceinline__ u16 f2bf(float x) {
  __hip_bfloat16 h = __float2bfloat16(x);
  u16 r; __builtin_memcpy(&r, &h, 2); return r;
}

// ---------------- normalize + cast to bf16 + diag ----------------
__global__ void norm_diag_kernel(const float* __restrict__ im,
                                 const float* __restrict__ tx,
                                 u16* __restrict__ imn,
                                 u16* __restrict__ txn,
                                 float* __restrict__ diag) {
  const int row = blockIdx.x;
  const int t = threadIdx.x;
  const size_t base = (size_t)row * D_SZ;
  float4 vi = reinterpret_cast<const float4*>(im + base)[t];
  float4 vt = reinterpret_cast<const float4*>(tx + base)[t];
  float ssi = vi.x * vi.x + vi.y * vi.y + vi.z * vi.z + vi.w * vi.w;
  float sst = vt.x * vt.x + vt.y * vt.y + vt.z * vt.z + vt.w * vt.w;
  float dot = vi.x * vt.x + vi.y * vt.y + vi.z * vt.z + vi.w * vt.w;
#pragma unroll
  for (int off = 32; off > 0; off >>= 1) {
    ssi += __shfl_down(ssi, off, 64);
    sst += __shfl_down(sst, off, 64);
    dot += __shfl_down(dot, off, 64);
  }
  __shared__ float w[3][4];
  if ((t & 63) == 0) { int wi = t >> 6; w[0][wi] = ssi; w[1][wi] = sst; w[2][wi] = dot; }
  __syncthreads();
  const float tssi = (w[0][0] + w[0][1]) + (w[0][2] + w[0][3]);
  const float tsst = (w[1][0] + w[1][1]) + (w[1][2] + w[1][3]);
  const float tdot = (w[2][0] + w[2][1]) + (w[2][2] + w[2][3]);
  const float si = 1.0f / fmaxf(sqrtf(tssi), 1e-12f);
  const float st = 1.0f / fmaxf(sqrtf(tsst), 1e-12f);
  u16 oi[4] = { f2bf(vi.x * si), f2bf(vi.y * si), f2bf(vi.z * si), f2bf(vi.w * si) };
  u16 ot[4] = { f2bf(vt.x * st), f2bf(vt.y * st), f2bf(vt.z * st), f2bf(vt.w * st) };
  ushort4 pi, pt; __builtin_memcpy(&pi, oi, 8); __builtin_memcpy(&pt, ot, 8);
  reinterpret_cast<ushort4*>(imn + base)[t] = pi;
  reinterpret_cast<ushort4*>(txn + base)[t] = pt;
  if (t == 0) diag[row] = tdot * si * st;
}

// ---------------- 256x256 GEMM, 16 waves, BK=64, fused hinge loss ----------
// Round-11: r10's GEMM (41.3 us, MfmaUtil 30.5%, VGPR 56 — the 4-wave/SIMD
// regime finally hides the barrier drains) with the hinge-loss epilogue
// RE-FUSED (r10's separate loss pass cost ~35 us re-reading the 64 MB sim;
// fused it rides under other blocks' K-loops as in r1-r8).
// 16 waves as 4M x 4N (64x64/wave), one barrier per K-tile, dbuf 128 KiB LDS,
// zero-conflict XOR involution layout, XCD-swizzled grid,
// __launch_bounds__(1024,4) keeps VGPR <=128 so the full block stays resident.
__device__ __forceinline__ void gload_lds16(const u16* g, u16* l) {
  __builtin_amdgcn_global_load_lds((__attribute__((address_space(1))) void*)g,
                                   (__attribute__((address_space(3))) void*)l,
                                   16, 0, 0);
}

__global__ __launch_bounds__(1024, 4) void gemm_loss_kernel(
    const u16* __restrict__ A,   // imn [4096][1024]
    const u16* __restrict__ Bt,  // txn [4096][1024]
    const float* __restrict__ diag,
    float* __restrict__ sim,     // d_out+1, row-major [4096][4096]
    float* __restrict__ loss) {
  __shared__ u16 sm[65536];      // 2 bufs x 4 regions x 8192 u16 = 128 KiB

  const int tid = threadIdx.x;
  const int l = tid & 63;
  const int w = tid >> 6;        // wave 0..15
  const int wr = w >> 2;         // 0..3  M quarter
  const int wc = w & 3;          // 0..3  N quarter
  const int ar = l & 15;
  const int arh = l >> 4;

  // XCD-aware bijective swizzle: 256 blocks, 8 XCDs, 32 consecutive per XCD.
  const int bid = blockIdx.x;
  const int s = (bid & 7) * 32 + (bid >> 3);
  const int tm = (s >> 4) * 256;
  const int tn = (s & 15) * 256;

  f32x4 acc[4][4] = {};

  // ---- staging: wave w stages rows 8w..8w+8 of each region ----
  const int l3 = l >> 3;
  const int cb = (l & 7) ^ l3;             // involution with read swizzle
  const int rho = w * 8 + l3;              // 0..127
  const u16* pR[4];
  pR[0] = A  + (size_t)(tm + rho)       * D_SZ + cb * 8;   // A0
  pR[1] = A  + (size_t)(tm + 128 + rho) * D_SZ + cb * 8;   // A1
  pR[2] = Bt + (size_t)(tn + rho)       * D_SZ + cb * 8;   // B0
  pR[3] = Bt + (size_t)(tn + 128 + rho) * D_SZ + cb * 8;   // B1

  // ---- read offsets (stored slot = (ks*4+arh) ^ (row&7); row&7 == ar&7) ----
  const int sl0 = (arh ^ (ar & 7)) * 8;
  const int sl1 = ((4 + arh) ^ (ar & 7)) * 8;
  const int aOfs = ((wr & 1) * 64 + ar) * 64;   // within region A(wr>>1)
  const int bOfs = ((wc & 1) * 64 + ar) * 64;   // within region B(wc>>1)
  const int aReg = wr >> 1;                     // 0..1
  const int bReg = 2 + (wc >> 1);               // 2..3

  // ---- prologue: stage K-tile 0 into buf 0 ----
#pragma unroll
  for (int c = 0; c < 4; c++)
    gload_lds16(pR[c], sm + c * 8192 + w * 512);
  __syncthreads();

#pragma unroll 1
  for (int t = 0; t < 16; ++t) {
    const int buf = t & 1;
    if (t + 1 < 16) {
      const int nb = buf ^ 1;
      const int ko = (t + 1) * 64;
#pragma unroll
      for (int c = 0; c < 4; c++)
        gload_lds16(pR[c] + ko, sm + (nb * 4 + c) * 8192 + w * 512);
    }
    const u16* Ab = sm + (buf * 4 + aReg) * 8192 + aOfs;
    const u16* Bb = sm + (buf * 4 + bReg) * 8192 + bOfs;
    {
      bf16x8 af[4], bfr[4];
#pragma unroll
      for (int m = 0; m < 4; m++) af[m] = *(const bf16x8*)&Ab[m * 1024 + sl0];
#pragma unroll
      for (int n = 0; n < 4; n++) bfr[n] = *(const bf16x8*)&Bb[n * 1024 + sl0];
#pragma unroll
      for (int m = 0; m < 4; m++)
#pragma unroll
        for (int n = 0; n < 4; n++)
          acc[m][n] = __builtin_amdgcn_mfma_f32_16x16x32_bf16(af[m], bfr[n], acc[m][n], 0, 0, 0);
    }
    {
      bf16x8 af[4], bfr[4];
#pragma unroll
      for (int m = 0; m < 4; m++) af[m] = *(const bf16x8*)&Ab[m * 1024 + sl1];
#pragma unroll
      for (int n = 0; n < 4; n++) bfr[n] = *(const bf16x8*)&Bb[n * 1024 + sl1];
#pragma unroll
      for (int m = 0; m < 4; m++)
#pragma unroll
        for (int n = 0; n < 4; n++)
          acc[m][n] = __builtin_amdgcn_mfma_f32_16x16x32_bf16(af[m], bfr[n], acc[m][n], 0, 0, 0);
    }
    __syncthreads();   // drains stage(t+1) + protects buf for stage(t+2)
  }

  // ---- epilogue: sim stores + fused hinge loss ----
  float dcs[4];
#pragma unroll
  for (int n = 0; n < 4; n++) dcs[n] = diag[tn + wc * 64 + n * 16 + ar];
  float lsum = 0.f;
#pragma unroll
  for (int m = 0; m < 4; m++) {
#pragma unroll
    for (int i = 0; i < 4; i++) {
      const int r = tm + wr * 64 + m * 16 + arh * 4 + i;
      const float dr = diag[r];
#pragma unroll
      for (int n = 0; n < 4; n++) {
        const int c = tn + wc * 64 + n * 16 + ar;
        const float s_ = acc[m][n][i];
        sim[(size_t)r * B_SZ + c] = s_;
        if (r != c)
          lsum += fmaxf(MARGIN + s_ - dr, 0.f) + fmaxf(MARGIN + s_ - dcs[n], 0.f);
      }
    }
  }
#pragma unroll
  for (int off = 32; off > 0; off >>= 1) lsum += __shfl_down(lsum, off, 64);
  if (l == 0) atomicAdd(loss, lsum);
}

extern "C" void kernel_launch(void* const* d_in, const int* in_sizes, int n_in,
                              void* d_out, int out_size, void* d_ws, size_t ws_size,
                              hipStream_t stream) {
  const float* im = (const float*)d_in[0];
  const float* tx = (const float*)d_in[1];
  float* out = (float*)d_out;
  float* loss = out;        // output 0: scalar total_loss
  float* sim = out + 1;     // output 1: [4096][4096]

  u16* imn = (u16*)d_ws;
  u16* txn = imn + (size_t)B_SZ * D_SZ;
  float* diag = (float*)(txn + (size_t)B_SZ * D_SZ);

  hipMemsetAsync(d_out, 0, sizeof(float), stream);
  norm_diag_kernel<<<B_SZ, 256, 0, stream>>>(im, tx, imn, txn, diag);
  gemm_loss_kernel<<<(B_SZ / 256) * (B_SZ / 256), 1024, 0, stream>>>(imn, txn, diag, sim, loss);
}

// Round 12
// 57.950 us; speedup vs baseline: 1.8001x; 1.8001x over previous
//
#include <hip/hip_runtime.h>
#include <hip/hip_bf16.h>

typedef unsigned short u16;
typedef __attribute__((ext_vector_type(8))) __bf16 bf16x8;
typedef __attribute__((ext_vector_type(4))) float f32x4;

#define B_SZ 4096
#define D_SZ 1024
#define MARGIN 0.2f

__device__ __forceinline__ u16 f2bf(float x) {
  __hip_bfloat16 h = __float2bfloat16(x);
  u16 r; __builtin_memcpy(&r, &h, 2); return r;
}

// ---------------- normalize + cast to bf16 + diag ----------------
__global__ void norm_diag_kernel(const float* __restrict__ im,
                                 const float* __restrict__ tx,
                                 u16* __restrict__ imn,
                                 u16* __restrict__ txn,
                                 float* __restrict__ diag) {
  const int row = blockIdx.x;
  const int t = threadIdx.x;
  const size_t base = (size_t)row * D_SZ;
  float4 vi = reinterpret_cast<const float4*>(im + base)[t];
  float4 vt = reinterpret_cast<const float4*>(tx + base)[t];
  float ssi = vi.x * vi.x + vi.y * vi.y + vi.z * vi.z + vi.w * vi.w;
  float sst = vt.x * vt.x + vt.y * vt.y + vt.z * vt.z + vt.w * vt.w;
  float dot = vi.x * vt.x + vi.y * vt.y + vi.z * vt.z + vi.w * vt.w;
#pragma unroll
  for (int off = 32; off > 0; off >>= 1) {
    ssi += __shfl_down(ssi, off, 64);
    sst += __shfl_down(sst, off, 64);
    dot += __shfl_down(dot, off, 64);
  }
  __shared__ float w[3][4];
  if ((t & 63) == 0) { int wi = t >> 6; w[0][wi] = ssi; w[1][wi] = sst; w[2][wi] = dot; }
  __syncthreads();
  const float tssi = (w[0][0] + w[0][1]) + (w[0][2] + w[0][3]);
  const float tsst = (w[1][0] + w[1][1]) + (w[1][2] + w[1][3]);
  const float tdot = (w[2][0] + w[2][1]) + (w[2][2] + w[2][3]);
  const float si = 1.0f / fmaxf(sqrtf(tssi), 1e-12f);
  const float st = 1.0f / fmaxf(sqrtf(tsst), 1e-12f);
  u16 oi[4] = { f2bf(vi.x * si), f2bf(vi.y * si), f2bf(vi.z * si), f2bf(vi.w * si) };
  u16 ot[4] = { f2bf(vt.x * st), f2bf(vt.y * st), f2bf(vt.z * st), f2bf(vt.w * st) };
  ushort4 pi, pt; __builtin_memcpy(&pi, oi, 8); __builtin_memcpy(&pt, ot, 8);
  reinterpret_cast<ushort4*>(imn + base)[t] = pi;
  reinterpret_cast<ushort4*>(txn + base)[t] = pt;
  if (t == 0) diag[row] = tdot * si * st;
}

// ---------------- 256x256 GEMM, 16 waves, BK=64, fused hinge loss ----------
// Round-12: r11 with the ATOMIC CONTENTION fixed. r11's 88.6us (vs r10's 41.3
// with identical main loop) was the tail of 4096 same-address atomicAdds
// (~28 cyc each, fully serialized since all 256 blocks are co-resident).
// Now: wave shfl-reduce -> LDS (reuse sm; K-loop done) -> block sum ->
// ONE atomicAdd per block (256 total ~ 3us, hidden by staggered finishes).
// This same tail explains the ~20-25us "fixed overhead" of rounds 4-7.
__device__ __forceinline__ void gload_lds16(const u16* g, u16* l) {
  __builtin_amdgcn_global_load_lds((__attribute__((address_space(1))) void*)g,
                                   (__attribute__((address_space(3))) void*)l,
                                   16, 0, 0);
}

__global__ __launch_bounds__(1024, 4) void gemm_loss_kernel(
    const u16* __restrict__ A,   // imn [4096][1024]
    const u16* __restrict__ Bt,  // txn [4096][1024]
    const float* __restrict__ diag,
    float* __restrict__ sim,     // d_out+1, row-major [4096][4096]
    float* __restrict__ loss) {
  __shared__ u16 sm[65536];      // 2 bufs x 4 regions x 8192 u16 = 128 KiB

  const int tid = threadIdx.x;
  const int l = tid & 63;
  const int w = tid >> 6;        // wave 0..15
  const int wr = w >> 2;         // 0..3  M quarter
  const int wc = w & 3;          // 0..3  N quarter
  const int ar = l & 15;
  const int arh = l >> 4;

  // XCD-aware bijective swizzle: 256 blocks, 8 XCDs, 32 consecutive per XCD.
  const int bid = blockIdx.x;
  const int s = (bid & 7) * 32 + (bid >> 3);
  const int tm = (s >> 4) * 256;
  const int tn = (s & 15) * 256;

  f32x4 acc[4][4] = {};

  // ---- staging: wave w stages rows 8w..8w+8 of each region ----
  const int l3 = l >> 3;
  const int cb = (l & 7) ^ l3;             // involution with read swizzle
  const int rho = w * 8 + l3;              // 0..127
  const u16* pR[4];
  pR[0] = A  + (size_t)(tm + rho)       * D_SZ + cb * 8;   // A0
  pR[1] = A  + (size_t)(tm + 128 + rho) * D_SZ + cb * 8;   // A1
  pR[2] = Bt + (size_t)(tn + rho)       * D_SZ + cb * 8;   // B0
  pR[3] = Bt + (size_t)(tn + 128 + rho) * D_SZ + cb * 8;   // B1

  // ---- read offsets (stored slot = (ks*4+arh) ^ (row&7); row&7 == ar&7) ----
  const int sl0 = (arh ^ (ar & 7)) * 8;
  const int sl1 = ((4 + arh) ^ (ar & 7)) * 8;
  const int aOfs = ((wr & 1) * 64 + ar) * 64;   // within region A(wr>>1)
  const int bOfs = ((wc & 1) * 64 + ar) * 64;   // within region B(wc>>1)
  const int aReg = wr >> 1;                     // 0..1
  const int bReg = 2 + (wc >> 1);               // 2..3

  // ---- prologue: stage K-tile 0 into buf 0 ----
#pragma unroll
  for (int c = 0; c < 4; c++)
    gload_lds16(pR[c], sm + c * 8192 + w * 512);
  __syncthreads();

#pragma unroll 1
  for (int t = 0; t < 16; ++t) {
    const int buf = t & 1;
    if (t + 1 < 16) {
      const int nb = buf ^ 1;
      const int ko = (t + 1) * 64;
#pragma unroll
      for (int c = 0; c < 4; c++)
        gload_lds16(pR[c] + ko, sm + (nb * 4 + c) * 8192 + w * 512);
    }
    const u16* Ab = sm + (buf * 4 + aReg) * 8192 + aOfs;
    const u16* Bb = sm + (buf * 4 + bReg) * 8192 + bOfs;
    {
      bf16x8 af[4], bfr[4];
#pragma unroll
      for (int m = 0; m < 4; m++) af[m] = *(const bf16x8*)&Ab[m * 1024 + sl0];
#pragma unroll
      for (int n = 0; n < 4; n++) bfr[n] = *(const bf16x8*)&Bb[n * 1024 + sl0];
#pragma unroll
      for (int m = 0; m < 4; m++)
#pragma unroll
        for (int n = 0; n < 4; n++)
          acc[m][n] = __builtin_amdgcn_mfma_f32_16x16x32_bf16(af[m], bfr[n], acc[m][n], 0, 0, 0);
    }
    {
      bf16x8 af[4], bfr[4];
#pragma unroll
      for (int m = 0; m < 4; m++) af[m] = *(const bf16x8*)&Ab[m * 1024 + sl1];
#pragma unroll
      for (int n = 0; n < 4; n++) bfr[n] = *(const bf16x8*)&Bb[n * 1024 + sl1];
#pragma unroll
      for (int m = 0; m < 4; m++)
#pragma unroll
        for (int n = 0; n < 4; n++)
          acc[m][n] = __builtin_amdgcn_mfma_f32_16x16x32_bf16(af[m], bfr[n], acc[m][n], 0, 0, 0);
    }
    __syncthreads();   // drains stage(t+1) + protects buf for stage(t+2)
  }

  // ---- epilogue: sim stores + fused hinge loss ----
  float dcs[4];
#pragma unroll
  for (int n = 0; n < 4; n++) dcs[n] = diag[tn + wc * 64 + n * 16 + ar];
  float lsum = 0.f;
#pragma unroll
  for (int m = 0; m < 4; m++) {
#pragma unroll
    for (int i = 0; i < 4; i++) {
      const int r = tm + wr * 64 + m * 16 + arh * 4 + i;
      const float dr = diag[r];
#pragma unroll
      for (int n = 0; n < 4; n++) {
        const int c = tn + wc * 64 + n * 16 + ar;
        const float s_ = acc[m][n][i];
        sim[(size_t)r * B_SZ + c] = s_;
        if (r != c)
          lsum += fmaxf(MARGIN + s_ - dr, 0.f) + fmaxf(MARGIN + s_ - dcs[n], 0.f);
      }
    }
  }
#pragma unroll
  for (int off = 32; off > 0; off >>= 1) lsum += __shfl_down(lsum, off, 64);

  // block-level reduction: ONE atomic per block (256 total), not per wave.
  float* wsum = (float*)sm;      // LDS reuse; K-loop fully done
  if (l == 0) wsum[w] = lsum;
  __syncthreads();
  if (tid == 0) {
    float tot = 0.f;
#pragma unroll
    for (int i = 0; i < 16; i++) tot += wsum[i];
    atomicAdd(loss, tot);
  }
}

extern "C" void kernel_launch(void* const* d_in, const int* in_sizes, int n_in,
                              void* d_out, int out_size, void* d_ws, size_t ws_size,
                              hipStream_t stream) {
  const float* im = (const float*)d_in[0];
  const float* tx = (const float*)d_in[1];
  float* out = (float*)d_out;
  float* loss = out;        // output 0: scalar total_loss
  float* sim = out + 1;     // output 1: [4096][4096]

  u16* imn = (u16*)d_ws;
  u16* txn = imn + (size_t)B_SZ * D_SZ;
  float* diag = (float*)(txn + (size_t)B_SZ * D_SZ);

  hipMemsetAsync(d_out, 0, sizeof(float), stream);
  norm_diag_kernel<<<B_SZ, 256, 0, stream>>>(im, tx, imn, txn, diag);
  gemm_loss_kernel<<<(B_SZ / 256) * (B_SZ / 256), 1024, 0, stream>>>(imn, txn, diag, sim, loss);
}

// Round 13
// 51.912 us; speedup vs baseline: 2.0095x; 1.1163x over previous
//
#include <hip/hip_runtime.h>
#include <hip/hip_bf16.h>

typedef unsigned short u16;
typedef __attribute__((ext_vector_type(8))) __bf16 bf16x8;
typedef __attribute__((ext_vector_type(4))) float f32x4;

#define B_SZ 4096
#define D_SZ 1024
#define MARGIN 0.2f

__device__ __forceinline__ u16 f2bf(float x) {
  __hip_bfloat16 h = __float2bfloat16(x);
  u16 r; __builtin_memcpy(&r, &h, 2); return r;
}

// ---------------- normalize + cast to bf16 + diag (wave-per-row) ----------
// Round-13: one WAVE per row (was: one 256-thread block per row with LDS +
// syncthreads cross-wave reduce). Lane loads 4 coalesced float4 (128 B/thr),
// three independent shfl_xor butterfly chains give every lane the row sums
// (no LDS, no barrier), coalesced ushort4 stores. Also zeroes loss (block 0)
// so the separate memset dispatch is gone.
__global__ __launch_bounds__(256) void norm_diag_kernel(
    const float* __restrict__ im, const float* __restrict__ tx,
    u16* __restrict__ imn, u16* __restrict__ txn,
    float* __restrict__ diag, float* __restrict__ loss) {
  const int l = threadIdx.x & 63;
  const int row = blockIdx.x * 4 + (threadIdx.x >> 6);
  if (blockIdx.x == 0 && threadIdx.x == 0) *loss = 0.f;
  const size_t base = (size_t)row * D_SZ;
  const float4* pi4 = reinterpret_cast<const float4*>(im + base);
  const float4* pt4 = reinterpret_cast<const float4*>(tx + base);
  float4 vi[4], vt[4];
#pragma unroll
  for (int k = 0; k < 4; k++) { vi[k] = pi4[l + 64 * k]; vt[k] = pt4[l + 64 * k]; }
  float ssi = 0.f, sst = 0.f, dot = 0.f;
#pragma unroll
  for (int k = 0; k < 4; k++) {
    ssi += vi[k].x * vi[k].x + vi[k].y * vi[k].y + vi[k].z * vi[k].z + vi[k].w * vi[k].w;
    sst += vt[k].x * vt[k].x + vt[k].y * vt[k].y + vt[k].z * vt[k].z + vt[k].w * vt[k].w;
    dot += vi[k].x * vt[k].x + vi[k].y * vt[k].y + vi[k].z * vt[k].z + vi[k].w * vt[k].w;
  }
#pragma unroll
  for (int off = 32; off > 0; off >>= 1) {   // butterfly: all lanes get sums
    ssi += __shfl_xor(ssi, off, 64);
    sst += __shfl_xor(sst, off, 64);
    dot += __shfl_xor(dot, off, 64);
  }
  const float si = 1.0f / fmaxf(sqrtf(ssi), 1e-12f);
  const float st = 1.0f / fmaxf(sqrtf(sst), 1e-12f);
#pragma unroll
  for (int k = 0; k < 4; k++) {
    u16 oi[4] = { f2bf(vi[k].x * si), f2bf(vi[k].y * si),
                  f2bf(vi[k].z * si), f2bf(vi[k].w * si) };
    u16 ot[4] = { f2bf(vt[k].x * st), f2bf(vt[k].y * st),
                  f2bf(vt[k].z * st), f2bf(vt[k].w * st) };
    ushort4 pi, pt; __builtin_memcpy(&pi, oi, 8); __builtin_memcpy(&pt, ot, 8);
    reinterpret_cast<ushort4*>(imn + base)[l + 64 * k] = pi;
    reinterpret_cast<ushort4*>(txn + base)[l + 64 * k] = pt;
  }
  if (l == 0) diag[row] = dot * si * st;
}

// ---------------- 256x256 GEMM, 16 waves, BK=64, fused hinge loss ----------
// r12 kernel UNCHANGED (40.8us, MfmaUtil 32%, 0 conflicts, 1 atomic/block).
__device__ __forceinline__ void gload_lds16(const u16* g, u16* l) {
  __builtin_amdgcn_global_load_lds((__attribute__((address_space(1))) void*)g,
                                   (__attribute__((address_space(3))) void*)l,
                                   16, 0, 0);
}

__global__ __launch_bounds__(1024, 4) void gemm_loss_kernel(
    const u16* __restrict__ A,   // imn [4096][1024]
    const u16* __restrict__ Bt,  // txn [4096][1024]
    const float* __restrict__ diag,
    float* __restrict__ sim,     // d_out+1, row-major [4096][4096]
    float* __restrict__ loss) {
  __shared__ u16 sm[65536];      // 2 bufs x 4 regions x 8192 u16 = 128 KiB

  const int tid = threadIdx.x;
  const int l = tid & 63;
  const int w = tid >> 6;        // wave 0..15
  const int wr = w >> 2;         // 0..3  M quarter
  const int wc = w & 3;          // 0..3  N quarter
  const int ar = l & 15;
  const int arh = l >> 4;

  // XCD-aware bijective swizzle: 256 blocks, 8 XCDs, 32 consecutive per XCD.
  const int bid = blockIdx.x;
  const int s = (bid & 7) * 32 + (bid >> 3);
  const int tm = (s >> 4) * 256;
  const int tn = (s & 15) * 256;

  f32x4 acc[4][4] = {};

  // ---- staging: wave w stages rows 8w..8w+8 of each region ----
  const int l3 = l >> 3;
  const int cb = (l & 7) ^ l3;             // involution with read swizzle
  const int rho = w * 8 + l3;              // 0..127
  const u16* pR[4];
  pR[0] = A  + (size_t)(tm + rho)       * D_SZ + cb * 8;   // A0
  pR[1] = A  + (size_t)(tm + 128 + rho) * D_SZ + cb * 8;   // A1
  pR[2] = Bt + (size_t)(tn + rho)       * D_SZ + cb * 8;   // B0
  pR[3] = Bt + (size_t)(tn + 128 + rho) * D_SZ + cb * 8;   // B1

  // ---- read offsets (stored slot = (ks*4+arh) ^ (row&7); row&7 == ar&7) ----
  const int sl0 = (arh ^ (ar & 7)) * 8;
  const int sl1 = ((4 + arh) ^ (ar & 7)) * 8;
  const int aOfs = ((wr & 1) * 64 + ar) * 64;   // within region A(wr>>1)
  const int bOfs = ((wc & 1) * 64 + ar) * 64;   // within region B(wc>>1)
  const int aReg = wr >> 1;                     // 0..1
  const int bReg = 2 + (wc >> 1);               // 2..3

  // ---- prologue: stage K-tile 0 into buf 0 ----
#pragma unroll
  for (int c = 0; c < 4; c++)
    gload_lds16(pR[c], sm + c * 8192 + w * 512);
  __syncthreads();

#pragma unroll 1
  for (int t = 0; t < 16; ++t) {
    const int buf = t & 1;
    if (t + 1 < 16) {
      const int nb = buf ^ 1;
      const int ko = (t + 1) * 64;
#pragma unroll
      for (int c = 0; c < 4; c++)
        gload_lds16(pR[c] + ko, sm + (nb * 4 + c) * 8192 + w * 512);
    }
    const u16* Ab = sm + (buf * 4 + aReg) * 8192 + aOfs;
    const u16* Bb = sm + (buf * 4 + bReg) * 8192 + bOfs;
    {
      bf16x8 af[4], bfr[4];
#pragma unroll
      for (int m = 0; m < 4; m++) af[m] = *(const bf16x8*)&Ab[m * 1024 + sl0];
#pragma unroll
      for (int n = 0; n < 4; n++) bfr[n] = *(const bf16x8*)&Bb[n * 1024 + sl0];
#pragma unroll
      for (int m = 0; m < 4; m++)
#pragma unroll
        for (int n = 0; n < 4; n++)
          acc[m][n] = __builtin_amdgcn_mfma_f32_16x16x32_bf16(af[m], bfr[n], acc[m][n], 0, 0, 0);
    }
    {
      bf16x8 af[4], bfr[4];
#pragma unroll
      for (int m = 0; m < 4; m++) af[m] = *(const bf16x8*)&Ab[m * 1024 + sl1];
#pragma unroll
      for (int n = 0; n < 4; n++) bfr[n] = *(const bf16x8*)&Bb[n * 1024 + sl1];
#pragma unroll
      for (int m = 0; m < 4; m++)
#pragma unroll
        for (int n = 0; n < 4; n++)
          acc[m][n] = __builtin_amdgcn_mfma_f32_16x16x32_bf16(af[m], bfr[n], acc[m][n], 0, 0, 0);
    }
    __syncthreads();   // drains stage(t+1) + protects buf for stage(t+2)
  }

  // ---- epilogue: sim stores + fused hinge loss ----
  float dcs[4];
#pragma unroll
  for (int n = 0; n < 4; n++) dcs[n] = diag[tn + wc * 64 + n * 16 + ar];
  float lsum = 0.f;
#pragma unroll
  for (int m = 0; m < 4; m++) {
#pragma unroll
    for (int i = 0; i < 4; i++) {
      const int r = tm + wr * 64 + m * 16 + arh * 4 + i;
      const float dr = diag[r];
#pragma unroll
      for (int n = 0; n < 4; n++) {
        const int c = tn + wc * 64 + n * 16 + ar;
        const float s_ = acc[m][n][i];
        sim[(size_t)r * B_SZ + c] = s_;
        if (r != c)
          lsum += fmaxf(MARGIN + s_ - dr, 0.f) + fmaxf(MARGIN + s_ - dcs[n], 0.f);
      }
    }
  }
#pragma unroll
  for (int off = 32; off > 0; off >>= 1) lsum += __shfl_down(lsum, off, 64);

  // block-level reduction: ONE atomic per block (256 total).
  float* wsum = (float*)sm;      // LDS reuse; K-loop fully done
  if (l == 0) wsum[w] = lsum;
  __syncthreads();
  if (tid == 0) {
    float tot = 0.f;
#pragma unroll
    for (int i = 0; i < 16; i++) tot += wsum[i];
    atomicAdd(loss, tot);
  }
}

extern "C" void kernel_launch(void* const* d_in, const int* in_sizes, int n_in,
                              void* d_out, int out_size, void* d_ws, size_t ws_size,
                              hipStream_t stream) {
  const float* im = (const float*)d_in[0];
  const float* tx = (const float*)d_in[1];
  float* out = (float*)d_out;
  float* loss = out;        // output 0: scalar total_loss
  float* sim = out + 1;     // output 1: [4096][4096]

  u16* imn = (u16*)d_ws;
  u16* txn = imn + (size_t)B_SZ * D_SZ;
  float* diag = (float*)(txn + (size_t)B_SZ * D_SZ);

  norm_diag_kernel<<<B_SZ / 4, 256, 0, stream>>>(im, tx, imn, txn, diag, loss);
  gemm_loss_kernel<<<(B_SZ / 256) * (B_SZ / 256), 1024, 0, stream>>>(imn, txn, diag, sim, loss);
}